// Round 13
// baseline (32913.916 us; speedup 1.0000x reference)
//
#include <hip/hip_runtime.h>
#include <hip/hip_bf16.h>
#include <hip/hip_fp16.h>
#include <math.h>

// Problem constants
constexpr int L    = 1024;
constexpr int B    = 64;
constexpr int H    = 512;
constexpr int ED   = 512;
constexpr int PSSM = 21;
constexpr int DIN  = ED + PSSM;    // 533
constexpr int LU   = 60;
constexpr int HB   = H * B;        // 32768 fp16 elements per ring slot
constexpr int NWG_DIR = 16;        // fat MFMA workgroups per direction
constexpr int UPW  = 32;           // hidden units per WG

typedef __attribute__((ext_vector_type(8))) _Float16 half8;    // MFMA fp16 frag
typedef __attribute__((ext_vector_type(4))) float f32x4;       // MFMA acc frag
typedef __attribute__((ext_vector_type(4))) unsigned short ushort4v;

__device__ __forceinline__ unsigned bf16_rne(float f) {
    unsigned u = __float_as_uint(f);
    return (u + 0x7FFFu + ((u >> 16) & 1u)) >> 16;
}
__device__ __forceinline__ float sigf(float x) {               // overflow-safe
    return 1.f / (1.f + __expf(-x));
}
__device__ __forceinline__ float tanhfast(float x) {           // clamped fast tanh
    float xc = fminf(fmaxf(x, -15.f), 15.f);
    float e  = __expf(2.f * xc);
    return (e - 1.f) / (e + 1.f);
}

// ---------------------------------------------------------------------------
// P0: E2[dir][sym][col] = embed[sym] . Wih_dir[col][0:512] + bih[col]+bhh[col]
// ---------------------------------------------------------------------------
__global__ __launch_bounds__(256) void prep_e2(
    const float* __restrict__ Wih_f, const float* __restrict__ Wih_b,
    const float* __restrict__ bih_f, const float* __restrict__ bhh_f,
    const float* __restrict__ bih_b, const float* __restrict__ bhh_b,
    const float* __restrict__ embed, float* __restrict__ E2)
{
    int idx  = blockIdx.x * 256 + threadIdx.x;   // 0 .. 81919
    int col  = idx & 2047;
    int rest = idx >> 11;
    int s    = rest % 20;
    int dir  = rest / 20;
    const float* W  = dir ? Wih_b : Wih_f;
    const float* er = embed + (size_t)s * ED;
    const float* wr = W + (size_t)col * DIN;
    float a = 0.f;
    #pragma unroll 8
    for (int k = 0; k < ED; ++k) a = fmaf(er[k], wr[k], a);
    a += (dir ? bih_b : bih_f)[col] + (dir ? bhh_b : bhh_f)[col];
    E2[idx] = a;
}

// ---------------------------------------------------------------------------
// P1: split Whh into fp16 hi/lo pair (2-product fp16 split)
// ---------------------------------------------------------------------------
__global__ __launch_bounds__(256) void prep_whh(
    const float* __restrict__ Whh_f, const float* __restrict__ Whh_b,
    unsigned short* __restrict__ hi, unsigned short* __restrict__ lo)
{
    int idx = blockIdx.x * 256 + threadIdx.x;    // 0 .. 2*2048*512-1
    const int NPD = 2048 * 512;
    float w = (idx < NPD) ? Whh_f[idx] : Whh_b[idx - NPD];
    __half h = __float2half_rn(w);
    __half l2 = __float2half_rn(w - __half2float(h));
    hi[idx] = __half_as_ushort(h);
    lo[idx] = __half_as_ushort(l2);
}

// ---------------------------------------------------------------------------
// P2: P16[t][b][k32] = fp16(pssm[t][b][k]) (K padded 21->32 with zeros)
// ---------------------------------------------------------------------------
__global__ __launch_bounds__(256) void prep_p16(
    const float* __restrict__ pssm, unsigned short* __restrict__ P16)
{
    int t = blockIdx.x, tid = threadIdx.x;
    int b = tid >> 2, ko = (tid & 3) * 8;
    const float* src = pssm + ((size_t)t * B + b) * PSSM;
    unsigned short* dst = P16 + ((size_t)t * B + b) * 32 + ko;
    #pragma unroll
    for (int j = 0; j < 8; ++j) {
        int k = ko + j;
        dst[j] = __half_as_ushort(__float2half_rn(k < PSSM ? src[k] : 0.f));
    }
}

// ---------------------------------------------------------------------------
// P3: Wp16[dir][row][k32] = fp16(Wih_dir[row][512+k]) (pssm cols, padded)
// ---------------------------------------------------------------------------
__global__ __launch_bounds__(256) void prep_wp16(
    const float* __restrict__ Wih_f, const float* __restrict__ Wih_b,
    unsigned short* __restrict__ Wp16)
{
    int idx = blockIdx.x * 256 + threadIdx.x;    // 0 .. 131071
    int k    = idx & 31;
    int row2 = idx >> 5;        // dir*2048 + row
    int dir  = row2 >> 11;
    int row  = row2 & 2047;
    const float* W = dir ? Wih_b : Wih_f;
    float v = (k < PSSM) ? W[(size_t)row * DIN + ED + k] : 0.f;
    Wp16[idx] = __half_as_ushort(__float2half_rn(v));
}

// ---------------------------------------------------------------------------
// K1: persistent bidirectional LSTM. 32 WGs (16/dir), 256 thr, 32 units/WG.
// Wave q = batch-quarter computes 8 gate-tiles (4 gates x 2 unit-halves) via
// mfma_f32_16x16x32_f16: pssm part as 1 MFMA chunk (pre-wait, fp16 packed),
// h part as 16 chunks x 2 products (Whh hi/lo streamed from L2).
// h exchange: fp16 [b][k] ring via LLC bypass; per-wave staging (wave q only
// needs its batch-quarter rows) with 2-phase vmcnt(8) pipeline; publish =
// LDS transpose + scalar dword bypass stores; 16 flags/dir, wave 0 polls
// (R5-R11 proven protocol).
// ---------------------------------------------------------------------------
__global__ __launch_bounds__(256, 1) void lstm_mfma(
    const float* __restrict__ E2, const unsigned short* __restrict__ P16,
    const int* __restrict__ seq,
    const unsigned short* __restrict__ Wp16,
    const unsigned short* __restrict__ WhhHi, const unsigned short* __restrict__ WhhLo,
    unsigned short* __restrict__ ring,         // [2dir][2slot][64b][512k] fp16
    unsigned short* __restrict__ hs16_f, unsigned short* __restrict__ hs16_b,
    int* __restrict__ flags)
{
    __shared__ unsigned short hsh[64 * 512];   // staged h [b][k], 64 KB
    __shared__ float wesh[20][136];            // E2 slice (8 tiles x 16u), 10.6 KB
    __shared__ unsigned short hbuf[64][40];    // publish transpose, 5 KB

    const int wg    = blockIdx.x;
    const int dir   = wg >> 4;
    const int wslot = wg & 15;
    const int j0    = wslot * UPW;
    const int tid   = threadIdx.x;
    const int l     = tid & 63;
    const int q     = tid >> 6;            // wave = batch-quarter
    const int u     = l & 15;              // unit-within-16 (n index) / A m-index
    const int kh    = l >> 4;              // quad
    const int m0    = q * 16 + kh * 4;     // base batch (+r)

    const float* E2d = E2 + (size_t)dir * 20 * 2048;
    const unsigned short* Wpd = Wp16 + (size_t)dir * 2048 * 32;
    const unsigned short* Whi = WhhHi + (size_t)dir * 2048 * 512;
    const unsigned short* Wlo = WhhLo + (size_t)dir * 2048 * 512;
    unsigned short* rbase = ring + (size_t)dir * 2 * HB;
    unsigned short* hs16 = dir ? hs16_b : hs16_f;
    int* flg = flags + dir * 64;

    // ---- one-time LDS fill: E2 slice (tile t2 = hh*4+g, col t2*16+u) ----
    for (int i = tid; i < 20 * 128; i += 256) {
        int sym = i >> 7, cc = i & 127;
        int t2 = cc >> 4, uu = cc & 15;
        int hh = t2 >> 2, g = t2 & 3;
        wesh[sym][cc] = E2d[(size_t)sym * 2048 + g * 512 + j0 + hh * 16 + uu];
    }
    __syncthreads();

    // B row offsets (shorts) per tile: row = g*512 + j0 + hh*16 + u
    size_t bro[8];   // Whh (x512)
    size_t bpo[8];   // Wp16 (x32)
    #pragma unroll
    for (int t2 = 0; t2 < 8; ++t2) {
        int hh = t2 >> 2, g = t2 & 3;
        int row = g * 512 + j0 + hh * 16 + u;
        bro[t2] = (size_t)row * 512 + kh * 8;
        bpo[t2] = (size_t)row * 32 + kh * 8;
    }

    float creg[2][4] = {{0.f,0.f,0.f,0.f},{0.f,0.f,0.f,0.f}};
    int dead = 0;

    for (int s = 0; s < L; ++s) {
        const int t = dir ? (L - 1 - s) : s;

        // ---- acc init from E2 (h-independent) ----
        f32x4 acc[8];
        int sb[4];
        #pragma unroll
        for (int r = 0; r < 4; ++r) sb[r] = seq[t * B + m0 + r];
        #pragma unroll
        for (int t2 = 0; t2 < 8; ++t2) {
            f32x4 a;
            #pragma unroll
            for (int r = 0; r < 4; ++r) a[r] = wesh[sb[r]][t2 * 16 + u];
            acc[t2] = a;
        }

        // ---- pssm part as one MFMA chunk (pre-wait; P16/Wp16 cached) ----
        {
            half8 ap = *(const half8*)(P16 + ((size_t)t * B + q * 16 + u) * 32 + kh * 8);
            #pragma unroll
            for (int t2 = 0; t2 < 8; ++t2) {
                half8 bp = *(const half8*)(Wpd + bpo[t2]);
                acc[t2] = __builtin_amdgcn_mfma_f32_16x16x32_f16(ap, bp, acc[t2], 0, 0, 0);
            }
        }

        // ---- wait: wave 0 polls the 16 per-WG flags ----
        if (s > 0 && tid < 64 && !dead) {
            const int* fp = flg + (l & 15);
            int it = 0;
            while (true) {
                int v;
                asm volatile("global_load_dword %0, %1, off sc0 sc1\n\t"
                             "s_waitcnt vmcnt(0)"
                             : "=v"(v) : "v"(fp) : "memory");
                if (__all(v >= s)) break;
                __builtin_amdgcn_s_sleep(1);
                if (++it > (1 << 17)) { dead = 1; break; }
            }
        }
        __syncthreads();

        // ---- per-wave staging: 16 KB (own batch-quarter rows), 2-phase ----
        {
            const unsigned short* src = rbase + ((s + 1) & 1) * HB + q * 8192;
            unsigned short* dst = hsh + q * 8192;
            uint4 va[16];
            #pragma unroll
            for (int i = 0; i < 8; ++i) {
                int idx16 = i * 64 + l;
                asm volatile("global_load_dwordx4 %0, %1, off sc0 sc1"
                             : "=&v"(va[i]) : "v"(src + idx16 * 8) : "memory");
            }
            #pragma unroll
            for (int i = 8; i < 16; ++i) {
                int idx16 = i * 64 + l;
                asm volatile("global_load_dwordx4 %0, %1, off sc0 sc1"
                             : "=&v"(va[i]) : "v"(src + idx16 * 8) : "memory");
            }
            asm volatile("s_waitcnt vmcnt(8)" ::: "memory");
            #pragma unroll
            for (int i = 0; i < 8; ++i)
                *(uint4*)&dst[(i * 64 + l) * 8] = va[i];
            asm volatile("s_waitcnt vmcnt(0)" ::: "memory");
            #pragma unroll
            for (int i = 8; i < 16; ++i)
                *(uint4*)&dst[(i * 64 + l) * 8] = va[i];
        }
        // no barrier: each wave reads only its own staged region

        // ---- recurrent GEMM: K=512, 16 chunks x 8 tiles x 2 products ----
        #pragma unroll 2
        for (int c = 0; c < 16; ++c) {
            half8 ah = *(const half8*)&hsh[(q * 16 + u) * 512 + c * 32 + kh * 8];
            #pragma unroll
            for (int t2 = 0; t2 < 8; ++t2) {
                half8 bh = *(const half8*)(Whi + bro[t2] + c * 32);
                half8 bl = *(const half8*)(Wlo + bro[t2] + c * 32);
                acc[t2] = __builtin_amdgcn_mfma_f32_16x16x32_f16(ah, bh, acc[t2], 0, 0, 0);
                acc[t2] = __builtin_amdgcn_mfma_f32_16x16x32_f16(ah, bl, acc[t2], 0, 0, 0);
            }
        }

        // ---- gates (in-lane), cell update, h -> LDS transpose buffer ----
        #pragma unroll
        for (int hh = 0; hh < 2; ++hh) {
            ushort4v hvv;
            #pragma unroll
            for (int r = 0; r < 4; ++r) {
                float iv = sigf(acc[hh * 4 + 0][r]);
                float fv = sigf(acc[hh * 4 + 1][r]);
                float gv = tanhfast(acc[hh * 4 + 2][r]);
                float ov = sigf(acc[hh * 4 + 3][r]);
                float cc2 = fv * creg[hh][r] + iv * gv;
                creg[hh][r] = cc2;
                float hv = ov * tanhfast(cc2);
                hbuf[m0 + r][hh * 16 + u] = __half_as_ushort(__float2half_rn(hv));
                hvv[r] = (unsigned short)bf16_rne(hv);
            }
            *(ushort4v*)&hs16[(size_t)t * HB + (size_t)(j0 + hh * 16 + u) * B + m0] = hvv;
        }
        __syncthreads();

        // ---- publish: 256 threads x 4 scalar dword bypass stores (4 KB) ----
        {
            int bb = tid >> 2, off = (tid & 3) * 8;
            unsigned short* d = rbase + (s & 1) * HB + bb * 512 + j0 + off;
            #pragma unroll
            for (int w2 = 0; w2 < 4; ++w2) {
                unsigned v = *(const unsigned*)&hbuf[bb][off + w2 * 2];
                asm volatile("global_store_dword %0, %1, off sc0 sc1"
                             :: "v"(d + w2 * 2), "v"(v) : "memory");
            }
        }
        __syncthreads();   // all waves drain vmcnt at barrier -> LLC-visible
        if (tid == 0) {
            int val = s + 1;
            asm volatile("global_store_dword %0, %1, off sc0 sc1"
                         :: "v"(flg + wslot), "v"(val) : "memory");
        }
    }
}

// ---------------------------------------------------------------------------
// K2: logits -> softmax -> alphabet mix -> normalized sin/cos of torsions.
// ---------------------------------------------------------------------------
__global__ __launch_bounds__(256) void proj_softmax(
    const __hip_bfloat16* __restrict__ hs16_f, const __hip_bfloat16* __restrict__ hs16_b,
    const float* __restrict__ W_lin, const float* __restrict__ b_lin,
    const float* __restrict__ alphabet, float* __restrict__ sp, float* __restrict__ cp)
{
    const int t   = blockIdx.x;
    const int tid = threadIdx.x;
    const int b   = tid & 63;
    const int ug  = __builtin_amdgcn_readfirstlane(tid >> 6);
    constexpr int NU = 15;

    __shared__ float lg[B][LU];
    __shared__ float sa[LU][3], ca[LU][3];
    if (tid < LU) {
        for (int k = 0; k < 3; ++k) {
            float a = alphabet[tid * 3 + k];
            sa[tid][k] = __sinf(a);
            ca[tid][k] = __cosf(a);
        }
    }

    const int u0 = ug * NU;
    float acc[NU];
    #pragma unroll
    for (int i = 0; i < NU; ++i) acc[i] = b_lin[u0 + i];

    const __hip_bfloat16* hf = hs16_f + (size_t)t * HB + b;
    const __hip_bfloat16* hb = hs16_b + (size_t)t * HB + b;
    #pragma unroll 4
    for (int j = 0; j < H; ++j) {
        float hv = __bfloat162float(hf[(size_t)j * B]);
        #pragma unroll
        for (int i = 0; i < NU; ++i)
            acc[i] = fmaf(hv, W_lin[(size_t)(u0 + i) * (2 * H) + j], acc[i]);
    }
    #pragma unroll 4
    for (int j = 0; j < H; ++j) {
        float hv = __bfloat162float(hb[(size_t)j * B]);
        #pragma unroll
        for (int i = 0; i < NU; ++i)
            acc[i] = fmaf(hv, W_lin[(size_t)(u0 + i) * (2 * H) + H + j], acc[i]);
    }
    #pragma unroll
    for (int i = 0; i < NU; ++i) lg[b][u0 + i] = acc[i];
    __syncthreads();

    if (tid < B) {
        float m = -1e30f;
        for (int u = 0; u < LU; ++u) m = fmaxf(m, lg[tid][u]);
        float sv[3] = {0, 0, 0}, cv[3] = {0, 0, 0};
        for (int u = 0; u < LU; ++u) {
            float e = __expf(lg[tid][u] - m);
            for (int k = 0; k < 3; ++k) {
                sv[k] = fmaf(e, sa[u][k], sv[k]);
                cv[k] = fmaf(e, ca[u][k], cv[k]);
            }
        }
        for (int k = 0; k < 3; ++k) {
            float r = rsqrtf(sv[k] * sv[k] + cv[k] * cv[k]);
            sp[((size_t)t * B + tid) * 3 + k] = sv[k] * r;
            cp[((size_t)t * B + tid) * 3 + k] = cv[k] * r;
        }
    }
}

// ---------------------------------------------------------------------------
// K3: sequential NeRF extension. One wave, lane = chain.
// ---------------------------------------------------------------------------
__global__ void geometry(const float* __restrict__ sp, const float* __restrict__ cp,
                         float* __restrict__ out)
{
    const int b = threadIdx.x;
    const float Rj[3] = {132.868f, 145.801f, 152.326f};
    const float Tj[3] = {2.028f, 2.124f, 1.941f};
    float cT[3], sT[3];
    for (int j = 0; j < 3; ++j) { cT[j] = cosf(Tj[j]); sT[j] = sinf(Tj[j]); }

    for (int r = 0; r < 3; ++r)
        for (int c = 0; c < 3; ++c)
            out[((size_t)r * B + b) * 3 + c] = (r == c) ? 1.f : 0.f;

    float Ax = 1.f, Ay = 0.f, Az = 0.f;
    float Bx = 0.f, By = 1.f, Bz = 0.f;
    float Cx = 0.f, Cy = 0.f, Cz = 1.f;

    for (int t = 0; t < L; ++t) {
        for (int j = 0; j < 3; ++j) {
            float sP = sp[((size_t)t * B + b) * 3 + j];
            float cP = cp[((size_t)t * B + b) * 3 + j];
            float d0 = -Rj[j] * cT[j];
            float d1 =  Rj[j] * cP * sT[j];
            float d2 =  Rj[j] * sP * sT[j];

            float bcx = Cx - Bx, bcy = Cy - By, bcz = Cz - Bz;
            float inv = rsqrtf(bcx * bcx + bcy * bcy + bcz * bcz);
            bcx *= inv; bcy *= inv; bcz *= inv;

            float abx = Bx - Ax, aby = By - Ay, abz = Bz - Az;
            float nx = aby * bcz - abz * bcy;
            float ny = abz * bcx - abx * bcz;
            float nz = abx * bcy - aby * bcx;
            inv = rsqrtf(nx * nx + ny * ny + nz * nz);
            nx *= inv; ny *= inv; nz *= inv;

            float mx = ny * bcz - nz * bcy;
            float my = nz * bcx - nx * bcz;
            float mz = nx * bcy - ny * bcx;

            float Dx = bcx * d0 + mx * d1 + nx * d2 + Cx;
            float Dy = bcy * d0 + my * d1 + ny * d2 + Cy;
            float Dz = bcz * d0 + mz * d1 + nz * d2 + Cz;

            size_t r = 3 + 3 * (size_t)t + j;
            out[(r * B + b) * 3 + 0] = Dx;
            out[(r * B + b) * 3 + 1] = Dy;
            out[(r * B + b) * 3 + 2] = Dz;

            Ax = Bx; Ay = By; Az = Bz;
            Bx = Cx; By = Cy; Bz = Cz;
            Cx = Dx; Cy = Dy; Cz = Dz;
        }
    }
}

// ---------------------------------------------------------------------------
extern "C" void kernel_launch(void* const* d_in, const int* in_sizes, int n_in,
                              void* d_out, int out_size, void* d_ws, size_t ws_size,
                              hipStream_t stream)
{
    const int*   seq      = (const int*)  d_in[0];
    const float* pssm     = (const float*)d_in[1];
    // d_in[2] = length (all full-length)
    const float* embed    = (const float*)d_in[3];
    const float* Wih_f    = (const float*)d_in[4];
    const float* Whh_f    = (const float*)d_in[5];
    const float* bih_f    = (const float*)d_in[6];
    const float* bhh_f    = (const float*)d_in[7];
    const float* Wih_b    = (const float*)d_in[8];
    const float* Whh_b    = (const float*)d_in[9];
    const float* bih_b    = (const float*)d_in[10];
    const float* bhh_b    = (const float*)d_in[11];
    const float* W_lin    = (const float*)d_in[12];
    const float* b_lin    = (const float*)d_in[13];
    const float* alphabet = (const float*)d_in[14];
    float* out = (float*)d_out;

    // workspace layout (~141 MB)
    char* ws = (char*)d_ws;
    unsigned short* ring  = (unsigned short*)ws;                        // 256 KB
    int* flags            = (int*)(ws + 262144);                        // 512 B
    size_t zero_bytes = 262656;
    float* E2             = (float*)(ws + 263168);                      // 320 KB
    unsigned short* P16   = (unsigned short*)(ws + 590848);             // 4 MB
    unsigned short* Wp16  = (unsigned short*)(ws + 590848 + 4194304);   // 256 KB
    unsigned short* WhhHi = (unsigned short*)(ws + 5047296);            // 4 MB
    unsigned short* WhhLo = (unsigned short*)(ws + 9241600);            // 4 MB
    unsigned short* hs16_f = (unsigned short*)(ws + 13435904);          // 64 MB
    unsigned short* hs16_b = (unsigned short*)(ws + 13435904 + 67108864);
    // sp/cp overlay E2/P16 region (dead after the LSTM kernel finishes)
    float* sp             = (float*)(ws + 263168);                      // 768 KB
    float* cp             = (float*)(ws + 263168 + 786432);             // 768 KB

    (void)hipMemsetAsync(ring, 0, zero_bytes, stream);   // ring + flags

    prep_e2<<<dim3(320), dim3(256), 0, stream>>>(Wih_f, Wih_b, bih_f, bhh_f,
                                                 bih_b, bhh_b, embed, E2);
    prep_whh<<<dim3(8192), dim3(256), 0, stream>>>(Whh_f, Whh_b, WhhHi, WhhLo);
    prep_p16<<<dim3(L), dim3(256), 0, stream>>>(pssm, P16);
    prep_wp16<<<dim3(512), dim3(256), 0, stream>>>(Wih_f, Wih_b, Wp16);

    lstm_mfma<<<dim3(2 * NWG_DIR), dim3(256), 0, stream>>>(
        E2, P16, seq, Wp16, WhhHi, WhhLo, ring, hs16_f, hs16_b, flags);

    proj_softmax<<<dim3(L), dim3(256), 0, stream>>>(
        (const __hip_bfloat16*)hs16_f, (const __hip_bfloat16*)hs16_b,
        W_lin, b_lin, alphabet, sp, cp);
    geometry<<<dim3(1), dim3(64), 0, stream>>>(sp, cp, out);
}